// Round 5
// baseline (268.830 us; speedup 1.0000x reference)
//
#include <hip/hip_runtime.h>
#include <hip/hip_bf16.h>
#include <stdint.h>

// CrossAttention: B=4 T=2048 HIN=1024 H=16 E=64
// prep(cvt X->bf16 + W transpose) -> all-bf16 proj GEMM (async LDS, XCD-aware grid)
// -> flash attn: 1-wave blocks (barrier-free), S^T=K*Q^T (P is A-fragment-native),
//    K frags direct from global (dense/coalesced), V via LDS double-buffer prefetched
//    at loop end, raw v_exp_f32 with LOG2E folded into Q.

typedef __bf16 bf16;
typedef __attribute__((ext_vector_type(8))) __bf16 bf16x8;
typedef __attribute__((ext_vector_type(4))) __bf16 bf16x4;
typedef __attribute__((ext_vector_type(4))) float f32x4;
typedef __attribute__((ext_vector_type(4))) short s16x4;

#define B_    4
#define T_    2048
#define HIN_  1024
#define H_    16
#define E_    64
#define NOUT_ 1024
#define LOG2E 1.4426950408889634f
#define QKSCALE 0.35355339059327373f   // 64^(-0.25)
#define QSCALE  (QKSCALE * LOG2E)      // fold log2(e) into Q so p = exp2(S) directly

__device__ __forceinline__ void gl_lds16(const void* g, void* l) {
  __builtin_amdgcn_global_load_lds((__attribute__((address_space(1))) void*)g,
                                   (__attribute__((address_space(3))) void*)l,
                                   16, 0, 0);
}

// ---- prep: X fp32->bf16 (blocks 0..8191) + W transpose/convert (blocks 8192..11263) ----
__global__ __launch_bounds__(256) void prep_kernel(const float* __restrict__ Xq,
                                                   const float* __restrict__ Xkv,
                                                   const float* __restrict__ Wq,
                                                   const float* __restrict__ Wk,
                                                   const float* __restrict__ Wv,
                                                   bf16* __restrict__ Xb,
                                                   bf16* __restrict__ Wt) {
  __shared__ float s[32][33];
  const int bid = blockIdx.x, tid = threadIdx.x;
  if (bid < 8192) {
    const float* src = (bid < 4096) ? Xq : Xkv;
    bf16* dst = Xb + (size_t)(bid >> 12) * (8192 * 1024);
    size_t i = ((size_t)(bid & 4095) * 256 + tid) * 8;
    float4 f0 = ((const float4*)(src + i))[0];
    float4 f1 = ((const float4*)(src + i))[1];
    bf16x8 t = {(bf16)f0.x, (bf16)f0.y, (bf16)f0.z, (bf16)f0.w,
                (bf16)f1.x, (bf16)f1.y, (bf16)f1.z, (bf16)f1.w};
    *(bf16x8*)(dst + i) = t;
  } else {
    const int wb = bid - 8192;       // 0..3071
    const int z = wb >> 10, r = wb & 1023;
    const float* W = (z == 0) ? Wq : ((z == 1) ? Wk : Wv);
    bf16* out = Wt + (size_t)z * HIN_ * NOUT_;
    const int n0 = (r & 31) * 32, k0 = (r >> 5) * 32;
    const int tx = tid & 31, ty = tid >> 5;
#pragma unroll
    for (int i = 0; i < 4; i++)
      s[ty + i * 8][tx] = W[(size_t)(k0 + ty + i * 8) * NOUT_ + n0 + tx];
    __syncthreads();
#pragma unroll
    for (int i = 0; i < 4; i++)
      out[(size_t)(n0 + ty + i * 8) * HIN_ + k0 + tx] = (bf16)s[tx][ty + i * 8];
  }
}

// ---- QKV projection, all-bf16, 128x128 tile, BK=64 ----
// grid (64, 8, 3). z<2: mt=bx (XCD=mt%8 -> A-tiles L2-resident), nt=by.
// z=2: nt=bx, mt=by.
__global__ __launch_bounds__(256, 4) void proj_kernel(const bf16* __restrict__ Xb,
                                                      const bf16* __restrict__ Wt,
                                                      bf16* __restrict__ Qb,
                                                      bf16* __restrict__ Kb,
                                                      bf16* __restrict__ Vtb) {
  __shared__ bf16 As[128 * 64];
  __shared__ bf16 Bs[128 * 64];
  const int z = blockIdx.z;
  const bf16* Abase = (z == 0) ? Xb : ((z == 1) ? Xb + (size_t)8192 * 1024 : Wt + (size_t)2 * HIN_ * NOUT_);
  const bf16* Bbase = (z == 0) ? Wt : ((z == 1) ? Wt + (size_t)HIN_ * NOUT_ : Xb + (size_t)8192 * 1024);
  const int mt = (z == 2) ? blockIdx.y : blockIdx.x;
  const int nt = (z == 2) ? blockIdx.x : blockIdx.y;
  const int m0 = mt * 128, n0 = nt * 128;
  const int tid = threadIdx.x;
  const int w = tid >> 6, lane = tid & 63, quad = lane >> 4, lo = lane & 15;
  const int wm = (w >> 1) * 64, wn = (w & 1) * 64;
  const int srow = w * 8 + (lane >> 3);
  const int schunk = (lane & 7) ^ (srow & 7);

  f32x4 acc[4][4] = {};

  for (int k0 = 0; k0 < HIN_; k0 += 64) {
    __syncthreads();
#pragma unroll
    for (int j = 0; j < 4; j++) {
      int row = j * 32 + srow;
      gl_lds16(Abase + (size_t)(m0 + row) * HIN_ + k0 + schunk * 8, As + (j * 32 + w * 8) * 64);
      gl_lds16(Bbase + (size_t)(n0 + row) * HIN_ + k0 + schunk * 8, Bs + (j * 32 + w * 8) * 64);
    }
    __syncthreads();
#pragma unroll
    for (int kk = 0; kk < 2; kk++) {
      bf16x8 bfrag[4], afrag[4];
#pragma unroll
      for (int j = 0; j < 4; j++) {
        int off = ((((kk << 2) + quad) ^ (lo & 7)) << 3);
        bfrag[j] = *(const bf16x8*)(Bs + (wn + j * 16 + lo) * 64 + off);
        afrag[j] = *(const bf16x8*)(As + (wm + j * 16 + lo) * 64 + off);
      }
#pragma unroll
      for (int i = 0; i < 4; i++)
#pragma unroll
        for (int j = 0; j < 4; j++)
          acc[i][j] = __builtin_amdgcn_mfma_f32_16x16x32_bf16(afrag[i], bfrag[j], acc[i][j], 0, 0, 0);
    }
  }

#pragma unroll
  for (int i = 0; i < 4; i++)
#pragma unroll
    for (int j = 0; j < 4; j++)
#pragma unroll
      for (int r = 0; r < 4; r++) {
        int m = m0 + wm + i * 16 + quad * 4 + r;
        int n = n0 + wn + j * 16 + lo;
        float v = acc[i][j][r];
        if (z == 2) {
          int h = m >> 6, e = m & 63, b = n >> 11, t = n & 2047;
          Vtb[(((size_t)b * H_ + h) * E_ + e) * T_ + t] = (bf16)v;
        } else {
          int b = m >> 11, t = m & 2047, h = n >> 6, e = n & 63;
          if (z == 0)
            Qb[(((size_t)b * H_ + h) * T_ + t) * E_ + e] = (bf16)(v * QSCALE);
          else
            Kb[(((size_t)b * H_ + h) * T_ + t) * E_ + e] = (bf16)(v * QKSCALE);
        }
      }
}

// ---- Flash attention: 1-wave blocks (barrier-free), 64 q/wave, 64-key tiles ----
// K frags direct from global (dense 2KB per load-group); V via LDS dbuf, prefetched at loop end.
__global__ __launch_bounds__(64, 2) void attn_kernel(const bf16* __restrict__ Qb,
                                                     const bf16* __restrict__ Kb,
                                                     const bf16* __restrict__ Vtb,
                                                     float* __restrict__ out) {
  __shared__ bf16 Vts[2][64 * 64];
  const int lane = threadIdx.x;
  const int quad = lane >> 4, lo = lane & 15;
  const int bh = blockIdx.x, wq = blockIdx.y * 64;
  const bf16* Qg = Qb + (size_t)bh * T_ * E_;
  const bf16* Kg = Kb + (size_t)bh * T_ * E_;
  const bf16* Vg = Vtb + (size_t)bh * E_ * T_;
  const int srow = lane >> 3;                 // 0..7: sub-row within 8-row staging group
  const int schunk = (lane & 7) ^ (srow & 7); // XOR'd source chunk (row&7 == srow&7)

  // Q fragments in registers (B-operand: n=lo -> q, k=quad*8+j -> e)
  bf16x8 qf[4][2];
#pragma unroll
  for (int qi = 0; qi < 4; qi++)
#pragma unroll
    for (int ks = 0; ks < 2; ks++)
      qf[qi][ks] = *(const bf16x8*)(Qg + (size_t)(wq + qi * 16 + lo) * E_ + ks * 32 + quad * 8);

  // prologue: stage V tile 0 into buf 0 (rows are e; cols are t)
#pragma unroll
  for (int i = 0; i < 8; i++)
    gl_lds16(Vg + (size_t)(i * 8 + srow) * T_ + schunk * 8, &Vts[0][i * 8 * 64]);

  f32x4 acc[4][4] = {};
  float lsum[4] = {0.f, 0.f, 0.f, 0.f};

  for (int kt = 0; kt < 32; kt++) {
    // K fragments direct from global (A-operand: m=lo -> t, k=quad*8+j -> e)
    bf16x8 kf[4][2];
#pragma unroll
    for (int ti = 0; ti < 4; ti++)
#pragma unroll
      for (int ks = 0; ks < 2; ks++)
        kf[ti][ks] = *(const bf16x8*)(Kg + (size_t)(kt * 64 + ti * 16 + lo) * E_ + ks * 32 + quad * 8);

    // S^T tiles + exp2 -> P fragments (A-layout for 16x16x16)
    bf16x4 pf[4][4];
#pragma unroll
    for (int qi = 0; qi < 4; qi++) {
      f32x4 st[4] = {};
#pragma unroll
      for (int ks = 0; ks < 2; ks++)
#pragma unroll
        for (int ti = 0; ti < 4; ti++)
          st[ti] = __builtin_amdgcn_mfma_f32_16x16x32_bf16(kf[ti][ks], qf[qi][ks], st[ti], 0, 0, 0);
      float ls = 0.f;
#pragma unroll
      for (int ti = 0; ti < 4; ti++) {
        bf16x4 p4;
#pragma unroll
        for (int r = 0; r < 4; r++) {
          float p = __builtin_amdgcn_exp2f(st[ti][r]);
          ls += p;
          p4[r] = (bf16)p;
        }
        pf[qi][ti] = p4;
      }
      lsum[qi] += ls;
    }

    // O += P @ V via 16x16x16 (B-operand: n=lo -> e, k=quad*4+j -> t)
    const bf16* vb = &Vts[kt & 1][0];
#pragma unroll
    for (int tc = 0; tc < 4; tc++)
#pragma unroll
      for (int ej = 0; ej < 4; ej++) {
        bf16x4 vf = *(const bf16x4*)(vb + (ej * 16 + lo) * 64 +
                                     (((tc * 2 + (quad >> 1)) ^ (lo & 7)) << 3) + (quad & 1) * 4);
#pragma unroll
        for (int qi = 0; qi < 4; qi++)
          acc[qi][ej] = __builtin_amdgcn_mfma_f32_16x16x16bf16_1k(
              __builtin_bit_cast(s16x4, pf[qi][tc]), __builtin_bit_cast(s16x4, vf),
              acc[qi][ej], 0, 0, 0);
      }

    // prefetch V tile kt+1 into the other buffer (wraps harmlessly on last iter)
    const int nt = (kt + 1) & 31;
    bf16* dst = &Vts[(kt + 1) & 1][0];
#pragma unroll
    for (int i = 0; i < 8; i++)
      gl_lds16(Vg + (size_t)(i * 8 + srow) * T_ + nt * 64 + schunk * 8, dst + i * 8 * 64);
  }

  const int b = bh >> 4, h = bh & 15;
#pragma unroll
  for (int qi = 0; qi < 4; qi++) {
    float l = lsum[qi];
    l += __shfl_xor(l, 16);
    l += __shfl_xor(l, 32);  // all quads hold full sum for q = qi*16+lo
#pragma unroll
    for (int r = 0; r < 4; r++) {
      float linv = __builtin_amdgcn_rcpf(__shfl(l, quad * 4 + r));
      size_t t = wq + qi * 16 + quad * 4 + r;
#pragma unroll
      for (int ej = 0; ej < 4; ej++)
        out[((size_t)b * T_ + t) * NOUT_ + h * E_ + ej * 16 + lo] = acc[qi][ej][r] * linv;
    }
  }
}

extern "C" void kernel_launch(void* const* d_in, const int* in_sizes, int n_in,
                              void* d_out, int out_size, void* d_ws, size_t ws_size,
                              hipStream_t stream) {
  const float* Xq  = (const float*)d_in[0];
  const float* Xkv = (const float*)d_in[1];
  const float* Wq  = (const float*)d_in[2];
  const float* Wk  = (const float*)d_in[3];
  const float* Wv  = (const float*)d_in[4];
  float* out = (float*)d_out;

  char* ws = (char*)d_ws;
  bf16* Qb  = (bf16*)(ws);                        // 16 MB [B][H][T][E]
  bf16* Kb  = (bf16*)(ws + ((size_t)16 << 20));   // 16 MB [B][H][T][E]
  bf16* Vtb = (bf16*)(ws + ((size_t)32 << 20));   // 16 MB [B][H][E][T]
  bf16* Wt  = (bf16*)(ws + ((size_t)48 << 20));   // 6 MB  3 x [N][K]
  bf16* Xb  = (bf16*)d_out;                       // 32 MB scratch (d_out unread until attn)

  hipLaunchKernelGGL(prep_kernel, dim3(11264), dim3(256), 0, stream, Xq, Xkv, Wq, Wk, Wv, Xb, Wt);
  hipLaunchKernelGGL(proj_kernel, dim3(64, 8, 3), dim3(256), 0, stream, Xb, Wt, Qb, Kb, Vtb);
  hipLaunchKernelGGL(attn_kernel, dim3(64, 32), dim3(64), 0, stream, Qb, Kb, Vtb, out);
}